// Round 6
// baseline (187.453 us; speedup 1.0000x reference)
//
#include <hip/hip_runtime.h>
#include <math.h>

#define NN 20000
#define NE 640000
#define HID 128
#define NH 8
#define HD 16
#define ATT_SCALE 0.25f

// counting-sort geometry
#define EPB 4096                 // edges per pass-1 block
#define NBLK1 157                // ceil(NE/EPB)
#define NBUCK 157                // ceil(NN/128), bucket = dst>>7 (128 nodes)
#define SCAN_N (NBUCK * NBLK1)   // 24649
#define SPT 25                   // 1024*25 = 25600 >= SCAN_N

typedef __attribute__((ext_vector_type(8))) short bhalf8;
typedef __attribute__((ext_vector_type(4))) float floatx4;

// ============================ CSR build: 2-level counting sort ============================
__global__ __launch_bounds__(256) void k_p1hist(const int* __restrict__ dst,
                                                int* __restrict__ cnt1) {
  __shared__ int h[NBUCK];
  int t = threadIdx.x, b = blockIdx.x;
  for (int i = t; i < NBUCK; i += 256) h[i] = 0;
  __syncthreads();
  int e0 = b * EPB;
#pragma unroll
  for (int it = 0; it < EPB / 256; ++it) {
    int e = e0 + it * 256 + t;
    if (e < NE) atomicAdd(&h[dst[e] >> 7], 1);
  }
  __syncthreads();
  for (int i = t; i < NBUCK; i += 256) cnt1[i * NBLK1 + b] = h[i];
}

__global__ __launch_bounds__(1024) void k_p1scan(int* __restrict__ cnt1,
                                                 int* __restrict__ boff) {
  __shared__ int sa[1024], sb[1024];
  int t = threadIdx.x;
  int base = t * SPT;
  int s = 0;
#pragma unroll 5
  for (int u = 0; u < SPT; ++u) {
    int i = base + u;
    s += (i < SCAN_N) ? cnt1[i] : 0;
  }
  sa[t] = s;
  __syncthreads();
  int* sp = sa;
  int* dp = sb;
  for (int st = 1; st < 1024; st <<= 1) {
    dp[t] = sp[t] + (t >= st ? sp[t - st] : 0);
    __syncthreads();
    int* tmp = sp; sp = dp; dp = tmp;
  }
  int run = sp[t] - s;  // exclusive prefix of this thread's chunk
#pragma unroll 5
  for (int u = 0; u < SPT; ++u) {
    int i = base + u;
    if (i < SCAN_N) {
      int v = cnt1[i];
      cnt1[i] = run;
      run += v;
    }
  }
  __syncthreads();
  for (int i = t; i < NBUCK; i += 1024) boff[i] = cnt1[i * NBLK1];
  if (t == 0) boff[NBUCK] = NE;
}

__global__ __launch_bounds__(256) void k_p1scat(const int* __restrict__ src,
                                                const int* __restrict__ dst,
                                                const int* __restrict__ cnt1,
                                                int2* __restrict__ tmp) {
  __shared__ int cur[NBUCK];
  int t = threadIdx.x, b = blockIdx.x;
  for (int i = t; i < NBUCK; i += 256) cur[i] = cnt1[i * NBLK1 + b];
  __syncthreads();
  int e0 = b * EPB;
#pragma unroll
  for (int it = 0; it < EPB / 256; ++it) {
    int e = e0 + it * 256 + t;
    if (e < NE) {
      int d = dst[e];
      int p = atomicAdd(&cur[d >> 7], 1);  // LDS atomic
      tmp[p] = make_int2(d, src[e]);
    }
  }
}

__global__ __launch_bounds__(256) void k_p2(const int2* __restrict__ tmp,
                                            const int* __restrict__ boff,
                                            int* __restrict__ off,
                                            int* __restrict__ srcs) {
  __shared__ int h[128], cur[128], sA[128], sB[128];
  int b = blockIdx.x, t = threadIdx.x;
  int lo = boff[b], hi = boff[b + 1];
  if (t < 128) h[t] = 0;
  __syncthreads();
  for (int i = lo + t; i < hi; i += 256) atomicAdd(&h[tmp[i].x & 127], 1);
  __syncthreads();
  if (t < 128) sA[t] = h[t];
  __syncthreads();
  int* sp = sA;
  int* dp = sB;
  for (int st = 1; st < 128; st <<= 1) {
    if (t < 128) dp[t] = sp[t] + (t >= st ? sp[t - st] : 0);
    __syncthreads();
    int* tm = sp; sp = dp; dp = tm;
  }
  if (t < 128) {
    int ex = sp[t] - h[t];  // exclusive within bucket
    cur[t] = ex;
    off[b * 128 + t] = lo + ex;  // empty trailing bins give off[NN]=NE
  }
  __syncthreads();
  for (int i = lo + t; i < hi; i += 256) {
    int2 v = tmp[i];
    int p = atomicAdd(&cur[v.x & 127], 1);  // LDS atomic
    srcs[lo + p] = v.y;
  }
}

// ============================ bf16 helpers ============================
__device__ __forceinline__ short f2b(float f) {  // RNE f32->bf16
  union { float f; unsigned u; } a;
  a.f = f;
  unsigned r = a.u + 0x7FFF + ((a.u >> 16) & 1);
  return (short)(r >> 16);
}

__device__ __forceinline__ float b2f(short s) {
  union { unsigned u; float f; } a;
  a.u = ((unsigned)(unsigned short)s) << 16;
  return a.f;
}

__device__ __forceinline__ bhalf8 load_a8(const float* __restrict__ p) {
  float4 x0 = *(const float4*)p;
  float4 x1 = *(const float4*)(p + 4);
  bhalf8 a;
  a[0] = f2b(x0.x); a[1] = f2b(x0.y); a[2] = f2b(x0.z); a[3] = f2b(x0.w);
  a[4] = f2b(x1.x); a[5] = f2b(x1.y); a[6] = f2b(x1.z); a[7] = f2b(x1.w);
  return a;
}

__global__ __launch_bounds__(256) void k_wconv(const float* __restrict__ W0,
                                               const float* __restrict__ W1,
                                               const float* __restrict__ W2,
                                               const float* __restrict__ W3,
                                               short* __restrict__ out) {
  int i = blockIdx.x * 256 + threadIdx.x;  // 65536 total
  int m = i >> 14;
  const float* src = (m == 0) ? W0 : (m == 1) ? W1 : (m == 2) ? W2 : W3;
  out[i] = f2b(src[i & 16383]);
}

// ============================ MFMA GEMM: O = X @ Wb^T + B ============================
// STRIDE==0: f32 row-major [r][HID] output (in-place safe: wave-private rows).
// STRIDE>0:  bf16 head-pair layout: out[((nt>>1)*NN + r)*STRIDE + HALF + (nt&1)*16 + rr]
//   Q: STRIDE=32 HALF=0;  K: STRIDE=64 HALF=0;  V: STRIDE=64 HALF=32 (K|V packed 128B).
template <int STRIDE, int HALF>
__device__ __forceinline__ void gemm_mfma(const float* __restrict__ X,
                                          const short* __restrict__ Wb,
                                          const float* __restrict__ B,
                                          void* __restrict__ O, int row_base) {
  int lane = threadIdx.x & 63;
  int w = threadIdx.x >> 6;
  int rr = lane & 15;
  int g = lane >> 4;
  int arow = row_base + w * 16 + rr;
  floatx4 acc[8];
#pragma unroll
  for (int nt = 0; nt < 8; ++nt) acc[nt] = (floatx4){0.f, 0.f, 0.f, 0.f};
  const float* xrow = X + (size_t)arow * HID;
#pragma unroll
  for (int kt = 0; kt < 4; ++kt) {
    bhalf8 a;
    if (arow < NN) {
      a = load_a8(xrow + kt * 32 + g * 8);
    } else {
      a = (bhalf8){0, 0, 0, 0, 0, 0, 0, 0};
    }
#pragma unroll
    for (int nt = 0; nt < 8; ++nt) {
      bhalf8 b = *(const bhalf8*)(Wb + (nt * 16 + rr) * HID + kt * 32 + g * 8);
      acc[nt] = __builtin_amdgcn_mfma_f32_16x16x32_bf16(a, b, acc[nt], 0, 0, 0);
    }
  }
  int orow0 = row_base + w * 16 + g * 4;
#pragma unroll
  for (int nt = 0; nt < 8; ++nt) {
    int col = nt * 16 + rr;
    float bias = B[col];
#pragma unroll
    for (int i = 0; i < 4; ++i) {
      int r = orow0 + i;
      if (r < NN) {
        float val = acc[nt][i] + bias;
        if (STRIDE == 0) {
          ((float*)O)[(size_t)r * HID + col] = val;
        } else {
          ((short*)O)[((size_t)(nt >> 1) * NN + r) * STRIDE + HALF +
                      (nt & 1) * 16 + rr] = f2b(val);
        }
      }
    }
  }
}

__global__ __launch_bounds__(256) void k_proj(
    const float* __restrict__ q, const float* __restrict__ k,
    const float* __restrict__ v, const short* __restrict__ Wb,
    const float* __restrict__ bq, const float* __restrict__ bk,
    const float* __restrict__ bv, short* __restrict__ Qh,
    short* __restrict__ KVh) {
  int row0 = blockIdx.x * 64;
  if (blockIdx.y == 0) gemm_mfma<32, 0>(q, Wb, bq, Qh, row0);
  else if (blockIdx.y == 1) gemm_mfma<64, 0>(k, Wb + 16384, bk, KVh, row0);
  else gemm_mfma<64, 32>(v, Wb + 2 * 16384, bv, KVh, row0);
}

__global__ __launch_bounds__(256) void k_gemm(const float* __restrict__ X,
                                              const short* __restrict__ Wb,
                                              const float* __restrict__ B,
                                              float* __restrict__ O) {
  gemm_mfma<0, 0>(X, Wb + 3 * 16384, B, O, blockIdx.x * 64);
}

// ============================ edge attention ============================
// 1250 blocks x 16 nodes; block loops hp=0..3 internally -> all blocks work on
// the same 2.56 MB K|V slice at a time (fits per-XCD L2). Edge list for the
// block's 16 nodes staged once in LDS (mean 512, cap 1024 w/ global fallback).
// 16 lanes per node: sub = hq + 2*j; merge 8 partials via shfl_xor {2,4,8}.
__global__ __launch_bounds__(256, 8) void k_edge(
    const int* __restrict__ off, const int* __restrict__ srcs,
    const short* __restrict__ Qh, const short* __restrict__ KVh,
    float* __restrict__ O) {
  __shared__ int els[1024];
  int t = threadIdx.x;
  int node0 = blockIdx.x * 16;
  int lo = off[node0], hi = off[node0 + 16];
  int cnt = hi - lo;
  int capped = cnt < 1024 ? cnt : 1024;
  for (int i = t; i < capped; i += 256) els[i] = srcs[lo + i];
  __syncthreads();
  int node = node0 + (t >> 4);
  int sub = t & 15;
  int hq = sub & 1;
  int j = sub >> 1;
  int i0 = off[node] - lo, i1 = off[node + 1] - lo;  // block-local indices
#pragma unroll
  for (int hp = 0; hp < 4; ++hp) {
    const short* qp = Qh + ((size_t)hp * NN + node) * 32 + hq * 16;
    bhalf8 q0 = *(const bhalf8*)qp;
    bhalf8 q1 = *(const bhalf8*)(qp + 8);
    float m = -1e30f, l = 0.f;
    float acc[16];
#pragma unroll
    for (int u = 0; u < 16; ++u) acc[u] = 0.f;
    for (int i = i0 + j; i < i1; i += 8) {
      int s = (i < 1024) ? els[i] : srcs[lo + i];
      const short* kv = KVh + ((size_t)hp * NN + s) * 64 + hq * 16;
      bhalf8 k0 = *(const bhalf8*)(kv);
      bhalf8 k1 = *(const bhalf8*)(kv + 8);
      bhalf8 v0 = *(const bhalf8*)(kv + 32);
      bhalf8 v1 = *(const bhalf8*)(kv + 40);
      float d0 = 0.f, d1 = 0.f;
#pragma unroll
      for (int u = 0; u < 8; ++u) d0 += b2f(q0[u]) * b2f(k0[u]);
#pragma unroll
      for (int u = 0; u < 8; ++u) d1 += b2f(q1[u]) * b2f(k1[u]);
      float sc = (d0 + d1) * ATT_SCALE;
      float nm = fmaxf(m, sc);
      float corr = __expf(m - nm);  // m=-1e30 first iter -> underflow 0
      float p = __expf(sc - nm);
      m = nm;
      l = l * corr + p;
#pragma unroll
      for (int u = 0; u < 8; ++u) acc[u] = acc[u] * corr + p * b2f(v0[u]);
#pragma unroll
      for (int u = 0; u < 8; ++u) acc[u + 8] = acc[u + 8] * corr + p * b2f(v1[u]);
    }
#pragma unroll
    for (int mask = 2; mask <= 8; mask <<= 1) {
      float m2 = __shfl_xor(m, mask, 64);
      float l2 = __shfl_xor(l, mask, 64);
      float nm = fmaxf(m, m2);
      float c1 = __expf(m - nm);
      float c2 = __expf(m2 - nm);
      l = l * c1 + l2 * c2;
#pragma unroll
      for (int u = 0; u < 16; ++u) {
        float a2 = __shfl_xor(acc[u], mask, 64);
        acc[u] = acc[u] * c1 + a2 * c2;
      }
      m = nm;
    }
    float inv = 1.f / (l + 1e-8f);  // degree 0 -> acc 0 -> out 0 (matches ref)
    float o0 = acc[0], o1 = acc[1];
#pragma unroll
    for (int jj = 1; jj < 8; ++jj) {
      if (j == jj) { o0 = acc[2 * jj]; o1 = acc[2 * jj + 1]; }
    }
    float2 o = make_float2(o0 * inv, o1 * inv);
    *(float2*)(O + (size_t)node * HID + hp * 32 + hq * 16 + j * 2) = o;
  }
}

// ============================ launch ============================
extern "C" void kernel_launch(void* const* d_in, const int* in_sizes, int n_in,
                              void* d_out, int out_size, void* d_ws,
                              size_t ws_size, hipStream_t stream) {
  const float* q = (const float*)d_in[0];
  const float* k = (const float*)d_in[1];
  const float* v = (const float*)d_in[2];
  const int* ei = (const int*)d_in[3];
  const float* Wq = (const float*)d_in[4];
  const float* bq = (const float*)d_in[5];
  const float* Wk = (const float*)d_in[6];
  const float* bk = (const float*)d_in[7];
  const float* Wv = (const float*)d_in[8];
  const float* bv = (const float*)d_in[9];
  const float* Wo = (const float*)d_in[10];
  const float* bo = (const float*)d_in[11];
  const int* src = ei;
  const int* dst = ei + NE;

  // workspace layout (16B-aligned sections)
  int2* tmp = (int2*)d_ws;                  // NE int2 = 5.12 MB
  int* srcs = (int*)(tmp + NE);             // NE
  int* cnt1 = srcs + NE;                    // 24704
  int* boff = cnt1 + 24704;                 // 160
  int* off = boff + 160;                    // 20104 (p2 writes 0..20095)
  short* Wb = (short*)(off + 20104);        // 4*16384 bf16
  short* Qh = Wb + 4 * 16384;               // [4][NN][32] bf16
  short* KVh = Qh + NN * HID;               // [4][NN][64] bf16 (K|V packed)
  float* O = (float*)d_out;

  k_wconv<<<256, 256, 0, stream>>>(Wq, Wk, Wv, Wo, Wb);
  k_p1hist<<<NBLK1, 256, 0, stream>>>(dst, cnt1);
  k_p1scan<<<1, 1024, 0, stream>>>(cnt1, boff);
  k_p1scat<<<NBLK1, 256, 0, stream>>>(src, dst, cnt1, tmp);
  k_p2<<<NBUCK, 256, 0, stream>>>(tmp, boff, off, srcs);

  dim3 pg((NN + 63) / 64, 3);
  k_proj<<<pg, 256, 0, stream>>>(q, k, v, Wb, bq, bk, bv, Qh, KVh);
  k_edge<<<1250, 256, 0, stream>>>(off, srcs, Qh, KVh, O);
  k_gemm<<<(NN + 63) / 64, 256, 0, stream>>>(O, Wb, bo, O);  // in-place safe
}

// Round 7
// 168.606 us; speedup vs baseline: 1.1118x; 1.1118x over previous
//
#include <hip/hip_runtime.h>
#include <math.h>

#define NN 20000
#define NE 640000
#define HID 128
#define NH 8
#define HD 16
#define ATT_SCALE 0.25f

// counting-sort geometry
#define EPB 4096                 // edges per pass-1 block
#define NBLK1 157                // ceil(NE/EPB)
#define NBUCK 157                // ceil(NN/128), bucket = dst>>7 (128 nodes)
#define SCAN_N (NBUCK * NBLK1)   // 24649
#define SPT 25                   // 1024*25 = 25600 >= SCAN_N

typedef __attribute__((ext_vector_type(8))) short bhalf8;
typedef __attribute__((ext_vector_type(4))) float floatx4;

// ============================ bf16 helpers ============================
__device__ __forceinline__ short f2b(float f) {  // RNE f32->bf16
  union { float f; unsigned u; } a;
  a.f = f;
  unsigned r = a.u + 0x7FFF + ((a.u >> 16) & 1);
  return (short)(r >> 16);
}

__device__ __forceinline__ float b2f(short s) {
  union { unsigned u; float f; } a;
  a.u = ((unsigned)(unsigned short)s) << 16;
  return a.f;
}

__device__ __forceinline__ bhalf8 load_a8(const float* __restrict__ p) {
  float4 x0 = *(const float4*)p;
  float4 x1 = *(const float4*)(p + 4);
  bhalf8 a;
  a[0] = f2b(x0.x); a[1] = f2b(x0.y); a[2] = f2b(x0.z); a[3] = f2b(x0.w);
  a[4] = f2b(x1.x); a[5] = f2b(x1.y); a[6] = f2b(x1.z); a[7] = f2b(x1.w);
  return a;
}

// ============================ fused: coarse histogram + weight convert ============================
// blocks [0, NBLK1): per-block LDS histogram over coarse buckets -> cnt1[bucket][blk]
// blocks [NBLK1, NBLK1+64): convert 4 weight matrices f32->bf16 (4 elems/thread)
__global__ __launch_bounds__(256) void k_hist_wconv(
    const int* __restrict__ dst, int* __restrict__ cnt1,
    const float* __restrict__ W0, const float* __restrict__ W1,
    const float* __restrict__ W2, const float* __restrict__ W3,
    short* __restrict__ out) {
  int t = threadIdx.x, b = blockIdx.x;
  if (b < NBLK1) {
    __shared__ int h[NBUCK];
    for (int i = t; i < NBUCK; i += 256) h[i] = 0;
    __syncthreads();
    int e0 = b * EPB;
#pragma unroll
    for (int it = 0; it < EPB / 256; ++it) {
      int e = e0 + it * 256 + t;
      if (e < NE) atomicAdd(&h[dst[e] >> 7], 1);
    }
    __syncthreads();
    for (int i = t; i < NBUCK; i += 256) cnt1[i * NBLK1 + b] = h[i];
  } else {
    int i = (b - NBLK1) * 1024 + t * 4;  // 64*1024 = 65536 total, 4 elems/thread
    int m = i >> 14;
    const float* src = (m == 0) ? W0 : (m == 1) ? W1 : (m == 2) ? W2 : W3;
    float4 x = *(const float4*)(src + (i & 16383));
    short4 o;
    o.x = f2b(x.x); o.y = f2b(x.y); o.z = f2b(x.z); o.w = f2b(x.w);
    *(short4*)(out + i) = o;
  }
}

__global__ __launch_bounds__(1024) void k_p1scan(int* __restrict__ cnt1,
                                                 int* __restrict__ boff) {
  __shared__ int sa[1024], sb[1024];
  int t = threadIdx.x;
  int base = t * SPT;
  int s = 0;
#pragma unroll 5
  for (int u = 0; u < SPT; ++u) {
    int i = base + u;
    s += (i < SCAN_N) ? cnt1[i] : 0;
  }
  sa[t] = s;
  __syncthreads();
  int* sp = sa;
  int* dp = sb;
  for (int st = 1; st < 1024; st <<= 1) {
    dp[t] = sp[t] + (t >= st ? sp[t - st] : 0);
    __syncthreads();
    int* tmp = sp; sp = dp; dp = tmp;
  }
  int run = sp[t] - s;  // exclusive prefix of this thread's chunk
#pragma unroll 5
  for (int u = 0; u < SPT; ++u) {
    int i = base + u;
    if (i < SCAN_N) {
      int v = cnt1[i];
      cnt1[i] = run;
      run += v;
    }
  }
  __syncthreads();
  for (int i = t; i < NBUCK; i += 1024) boff[i] = cnt1[i * NBLK1];
  if (t == 0) boff[NBUCK] = NE;
}

// p1c: scatter packed (src<<7 | dst&127) into bucket-major tmp (LDS cursors)
__global__ __launch_bounds__(256) void k_p1scat(const int* __restrict__ src,
                                                const int* __restrict__ dst,
                                                const int* __restrict__ cnt1,
                                                int* __restrict__ tmp) {
  __shared__ int cur[NBUCK];
  int t = threadIdx.x, b = blockIdx.x;
  for (int i = t; i < NBUCK; i += 256) cur[i] = cnt1[i * NBLK1 + b];
  __syncthreads();
  int e0 = b * EPB;
#pragma unroll
  for (int it = 0; it < EPB / 256; ++it) {
    int e = e0 + it * 256 + t;
    if (e < NE) {
      int d = dst[e];
      int p = atomicAdd(&cur[d >> 7], 1);  // LDS atomic
      tmp[p] = (src[e] << 7) | (d & 127);
    }
  }
}

// p2: per bucket, 128-bin LDS hist + scan -> final srcs (node-contiguous) + off[]
__global__ __launch_bounds__(256) void k_p2(const int* __restrict__ tmp,
                                            const int* __restrict__ boff,
                                            int* __restrict__ off,
                                            int* __restrict__ srcs) {
  __shared__ int h[128], cur[128], sA[128], sB[128];
  int b = blockIdx.x, t = threadIdx.x;
  int lo = boff[b], hi = boff[b + 1];
  if (t < 128) h[t] = 0;
  __syncthreads();
  for (int i = lo + t; i < hi; i += 256) atomicAdd(&h[tmp[i] & 127], 1);
  __syncthreads();
  if (t < 128) sA[t] = h[t];
  __syncthreads();
  int* sp = sA;
  int* dp = sB;
  for (int st = 1; st < 128; st <<= 1) {
    if (t < 128) dp[t] = sp[t] + (t >= st ? sp[t - st] : 0);
    __syncthreads();
    int* tm = sp; sp = dp; dp = tm;
  }
  if (t < 128) {
    int ex = sp[t] - h[t];  // exclusive within bucket
    cur[t] = ex;
    off[b * 128 + t] = lo + ex;  // empty trailing bins give off[NN]=NE
  }
  __syncthreads();
  for (int i = lo + t; i < hi; i += 256) {
    int w = tmp[i];
    int p = atomicAdd(&cur[w & 127], 1);  // LDS atomic
    srcs[lo + p] = w >> 7;
  }
}

// ============================ MFMA GEMM: O = X @ Wb^T + B ============================
// STRIDE==0: f32 row-major [r][HID] output (in-place safe: wave-private rows).
// STRIDE>0:  bf16 head-pair layout: out[((nt>>1)*NN + r)*STRIDE + HALF + (nt&1)*16 + rr]
//   Q: STRIDE=32 HALF=0;  K: STRIDE=64 HALF=0;  V: STRIDE=64 HALF=32 (K|V packed 128B).
template <int STRIDE, int HALF>
__device__ __forceinline__ void gemm_mfma(const float* __restrict__ X,
                                          const short* __restrict__ Wb,
                                          const float* __restrict__ B,
                                          void* __restrict__ O, int row_base) {
  int lane = threadIdx.x & 63;
  int w = threadIdx.x >> 6;
  int rr = lane & 15;
  int g = lane >> 4;
  int arow = row_base + w * 16 + rr;
  floatx4 acc[8];
#pragma unroll
  for (int nt = 0; nt < 8; ++nt) acc[nt] = (floatx4){0.f, 0.f, 0.f, 0.f};
  const float* xrow = X + (size_t)arow * HID;
#pragma unroll
  for (int kt = 0; kt < 4; ++kt) {
    bhalf8 a;
    if (arow < NN) {
      a = load_a8(xrow + kt * 32 + g * 8);
    } else {
      a = (bhalf8){0, 0, 0, 0, 0, 0, 0, 0};
    }
#pragma unroll
    for (int nt = 0; nt < 8; ++nt) {
      bhalf8 b = *(const bhalf8*)(Wb + (nt * 16 + rr) * HID + kt * 32 + g * 8);
      acc[nt] = __builtin_amdgcn_mfma_f32_16x16x32_bf16(a, b, acc[nt], 0, 0, 0);
    }
  }
  int orow0 = row_base + w * 16 + g * 4;
#pragma unroll
  for (int nt = 0; nt < 8; ++nt) {
    int col = nt * 16 + rr;
    float bias = B[col];
#pragma unroll
    for (int i = 0; i < 4; ++i) {
      int r = orow0 + i;
      if (r < NN) {
        float val = acc[nt][i] + bias;
        if (STRIDE == 0) {
          ((float*)O)[(size_t)r * HID + col] = val;
        } else {
          ((short*)O)[((size_t)(nt >> 1) * NN + r) * STRIDE + HALF +
                      (nt & 1) * 16 + rr] = f2b(val);
        }
      }
    }
  }
}

__global__ __launch_bounds__(256) void k_proj(
    const float* __restrict__ q, const float* __restrict__ k,
    const float* __restrict__ v, const short* __restrict__ Wb,
    const float* __restrict__ bq, const float* __restrict__ bk,
    const float* __restrict__ bv, short* __restrict__ Qh,
    short* __restrict__ KVh) {
  int row0 = blockIdx.x * 64;
  if (blockIdx.y == 0) gemm_mfma<32, 0>(q, Wb, bq, Qh, row0);
  else if (blockIdx.y == 1) gemm_mfma<64, 0>(k, Wb + 16384, bk, KVh, row0);
  else gemm_mfma<64, 32>(v, Wb + 2 * 16384, bv, KVh, row0);
}

__global__ __launch_bounds__(256) void k_gemm(const float* __restrict__ X,
                                              const short* __restrict__ Wb,
                                              const float* __restrict__ B,
                                              float* __restrict__ O) {
  gemm_mfma<0, 0>(X, Wb + 3 * 16384, B, O, blockIdx.x * 64);
}

// ============================ edge attention ============================
// 2500 blocks x 8 nodes (128 threads, 16 lanes/node); block loops hp=0..3 so
// all blocks sweep the same 2.56 MB K|V slice together (fits per-XCD L2).
// Pairwise edge processing: 2 edges/iter -> one combined softmax update
// (max3 + single corr + 3-FMA accumulate), 2 gathers in flight per lane.
// 16 lanes per node: sub = hq + 2*j; merge 8 partials via shfl_xor {2,4,8}.
__global__ __launch_bounds__(128, 6) void k_edge(
    const int* __restrict__ off, const int* __restrict__ srcs,
    const short* __restrict__ Qh, const short* __restrict__ KVh,
    float* __restrict__ O) {
  __shared__ int els[512];
  int t = threadIdx.x;
  int node0 = blockIdx.x * 8;
  int lo = off[node0], hi = off[node0 + 8];
  int cnt = hi - lo;
  int capped = cnt < 512 ? cnt : 512;
  for (int i = t; i < capped; i += 128) els[i] = srcs[lo + i];
  __syncthreads();
  int node = node0 + (t >> 4);
  int sub = t & 15;
  int hq = sub & 1;
  int j = sub >> 1;
  int i0 = off[node] - lo, i1 = off[node + 1] - lo;  // block-local indices
#pragma unroll
  for (int hp = 0; hp < 4; ++hp) {
    const short* qp = Qh + ((size_t)hp * NN + node) * 32 + hq * 16;
    bhalf8 q0 = *(const bhalf8*)qp;
    bhalf8 q1 = *(const bhalf8*)(qp + 8);
    float qf[16];
#pragma unroll
    for (int u = 0; u < 8; ++u) { qf[u] = b2f(q0[u]); qf[u + 8] = b2f(q1[u]); }
    float m = -1e30f, l = 0.f;
    float acc[16];
#pragma unroll
    for (int u = 0; u < 16; ++u) acc[u] = 0.f;
    int i = i0 + j;
    for (; i + 8 < i1; i += 16) {  // two edges per iteration
      int s1 = (i < 512) ? els[i] : srcs[lo + i];
      int s2 = (i + 8 < 512) ? els[i + 8] : srcs[lo + i + 8];
      const short* kv1 = KVh + ((size_t)hp * NN + s1) * 64 + hq * 16;
      const short* kv2 = KVh + ((size_t)hp * NN + s2) * 64 + hq * 16;
      bhalf8 ka0 = *(const bhalf8*)(kv1);
      bhalf8 ka1 = *(const bhalf8*)(kv1 + 8);
      bhalf8 va0 = *(const bhalf8*)(kv1 + 32);
      bhalf8 va1 = *(const bhalf8*)(kv1 + 40);
      bhalf8 kb0 = *(const bhalf8*)(kv2);
      bhalf8 kb1 = *(const bhalf8*)(kv2 + 8);
      bhalf8 vb0 = *(const bhalf8*)(kv2 + 32);
      bhalf8 vb1 = *(const bhalf8*)(kv2 + 40);
      float d1 = 0.f, d2 = 0.f;
#pragma unroll
      for (int u = 0; u < 8; ++u) {
        d1 += qf[u] * b2f(ka0[u]) + qf[u + 8] * b2f(ka1[u]);
        d2 += qf[u] * b2f(kb0[u]) + qf[u + 8] * b2f(kb1[u]);
      }
      float sc1 = d1 * ATT_SCALE, sc2 = d2 * ATT_SCALE;
      float nm = fmaxf(fmaxf(m, sc1), sc2);  // v_max3
      float corr = __expf(m - nm);
      float p1 = __expf(sc1 - nm);
      float p2 = __expf(sc2 - nm);
      m = nm;
      l = l * corr + p1 + p2;
#pragma unroll
      for (int u = 0; u < 8; ++u) {
        acc[u] = acc[u] * corr + p1 * b2f(va0[u]) + p2 * b2f(vb0[u]);
        acc[u + 8] = acc[u + 8] * corr + p1 * b2f(va1[u]) + p2 * b2f(vb1[u]);
      }
    }
    if (i < i1) {  // tail: at most one edge left per lane
      int s1 = (i < 512) ? els[i] : srcs[lo + i];
      const short* kv1 = KVh + ((size_t)hp * NN + s1) * 64 + hq * 16;
      bhalf8 ka0 = *(const bhalf8*)(kv1);
      bhalf8 ka1 = *(const bhalf8*)(kv1 + 8);
      bhalf8 va0 = *(const bhalf8*)(kv1 + 32);
      bhalf8 va1 = *(const bhalf8*)(kv1 + 40);
      float d1 = 0.f;
#pragma unroll
      for (int u = 0; u < 8; ++u)
        d1 += qf[u] * b2f(ka0[u]) + qf[u + 8] * b2f(ka1[u]);
      float sc1 = d1 * ATT_SCALE;
      float nm = fmaxf(m, sc1);
      float corr = __expf(m - nm);
      float p1 = __expf(sc1 - nm);
      m = nm;
      l = l * corr + p1;
#pragma unroll
      for (int u = 0; u < 8; ++u) {
        acc[u] = acc[u] * corr + p1 * b2f(va0[u]);
        acc[u + 8] = acc[u + 8] * corr + p1 * b2f(va1[u]);
      }
    }
#pragma unroll
    for (int mask = 2; mask <= 8; mask <<= 1) {
      float m2 = __shfl_xor(m, mask, 64);
      float l2 = __shfl_xor(l, mask, 64);
      float nm = fmaxf(m, m2);
      float c1 = __expf(m - nm);
      float c2 = __expf(m2 - nm);
      l = l * c1 + l2 * c2;
#pragma unroll
      for (int u = 0; u < 16; ++u) {
        float a2 = __shfl_xor(acc[u], mask, 64);
        acc[u] = acc[u] * c1 + a2 * c2;
      }
      m = nm;
    }
    float inv = 1.f / (l + 1e-8f);  // degree 0 -> acc 0 -> out 0 (matches ref)
    float o0 = acc[0], o1 = acc[1];
#pragma unroll
    for (int jj = 1; jj < 8; ++jj) {
      if (j == jj) { o0 = acc[2 * jj]; o1 = acc[2 * jj + 1]; }
    }
    float2 o = make_float2(o0 * inv, o1 * inv);
    *(float2*)(O + (size_t)node * HID + hp * 32 + hq * 16 + j * 2) = o;
  }
}

// ============================ launch ============================
extern "C" void kernel_launch(void* const* d_in, const int* in_sizes, int n_in,
                              void* d_out, int out_size, void* d_ws,
                              size_t ws_size, hipStream_t stream) {
  const float* q = (const float*)d_in[0];
  const float* k = (const float*)d_in[1];
  const float* v = (const float*)d_in[2];
  const int* ei = (const int*)d_in[3];
  const float* Wq = (const float*)d_in[4];
  const float* bq = (const float*)d_in[5];
  const float* Wk = (const float*)d_in[6];
  const float* bk = (const float*)d_in[7];
  const float* Wv = (const float*)d_in[8];
  const float* bv = (const float*)d_in[9];
  const float* Wo = (const float*)d_in[10];
  const float* bo = (const float*)d_in[11];
  const int* src = ei;
  const int* dst = ei + NE;

  // workspace layout (16B-aligned sections)
  int* tmp = (int*)d_ws;                    // NE ints (packed src<<7|bin)
  int* srcs = tmp + NE;                     // NE
  int* cnt1 = srcs + NE;                    // 24704
  int* boff = cnt1 + 24704;                 // 160
  int* off = boff + 160;                    // 20104 (p2 writes 0..20095)
  short* Wb = (short*)(off + 20104);        // 4*16384 bf16
  short* Qh = Wb + 4 * 16384;               // [4][NN][32] bf16
  short* KVh = Qh + NN * HID;               // [4][NN][64] bf16 (K|V packed)
  float* O = (float*)d_out;

  k_hist_wconv<<<NBLK1 + 64, 256, 0, stream>>>(dst, cnt1, Wq, Wk, Wv, Wo, Wb);
  k_p1scan<<<1, 1024, 0, stream>>>(cnt1, boff);
  k_p1scat<<<NBLK1, 256, 0, stream>>>(src, dst, cnt1, tmp);
  k_p2<<<NBUCK, 256, 0, stream>>>(tmp, boff, off, srcs);

  dim3 pg((NN + 63) / 64, 3);
  k_proj<<<pg, 256, 0, stream>>>(q, k, v, Wb, bq, bk, bv, Qh, KVh);
  k_edge<<<2500, 128, 0, stream>>>(off, srcs, Qh, KVh, O);
  k_gemm<<<(NN + 63) / 64, 256, 0, stream>>>(O, Wb, bo, O);  // in-place safe
}